// Round 1
// baseline (150.477 us; speedup 1.0000x reference)
//
#include <hip/hip_runtime.h>

// Batched Thomas solve, B=2048 rows, N=8192, fp32.
// One block per row; TB=1024 threads x CH=8-element contiguous chunks.
//
// R5 vs R4 (theory: VALU-op-count + serial-chain bound; VALUBusy 65%, HBM 24%):
//  1) Split the single 7-param projective scan into
//       - 4-param 2x2 Mobius scan for cp   (compose: 8 FMA vs 19 ops)
//       - 2-param affine scan for dp       (compose: 3 ops)
//     cp-path arithmetic is IDENTICAL to R4's (p,q,u,v) subrecurrence.
//  2) Cross-wave prefix loops propagate only the applied COLUMN (4 FMA/wave
//     vs 19), since the prefix is only ever applied to the init state (0,1).
//  3) Phase C runs the homogeneous (x,y,z) sweep: serial chain is 2 FMA per
//     element; v_rcp_f32 moves OFF the dependency chain. The dp-chunk affine
//     map (A = prod(-a_i)*rcp(z_CH), B = y_CH*rcp(z_CH)) falls out free.
// Cost: one extra __syncthreads + 8B/wave LDS for dp wave totals.

#define NN 8192
#define TB 1024
#define CH 8           // NN / TB
#define NWAVE (TB/64)  // 16

__device__ __forceinline__ float frcp(float x) { return __builtin_amdgcn_rcpf(x); }

__global__ __launch_bounds__(TB, 8)
void thomas_scan_kernel(const float* __restrict__ alpha,
                        const float* __restrict__ fvec,
                        float* __restrict__ out)
{
    __shared__ __align__(16) float wtot[NWAVE][4];  // cp 2x2 wave totals (p,q,u,v)
    __shared__ __align__(8)  float dtot[NWAVE][2];  // dp affine wave totals (A,B)
    __shared__ __align__(8)  float btot[NWAVE][2];  // backward affine wave totals

    const int t    = threadIdx.x;
    const int lane = t & 63;
    const int wid  = t >> 6;
    const int row  = blockIdx.x;
    const float* __restrict__ arow = alpha + (size_t)row * NN;
    const int base = t * CH;

    // ---- load alpha chunk + halo, f chunk into registers ----
    float va[CH], vf[CH];
    {
        const float4* a4 = reinterpret_cast<const float4*>(arow + base);
        const float4* f4 = reinterpret_cast<const float4*>(fvec + base);
        #pragma unroll
        for (int k = 0; k < CH / 4; ++k) {
            float4 x = a4[k];
            va[4*k+0]=x.x; va[4*k+1]=x.y; va[4*k+2]=x.z; va[4*k+3]=x.w;
            float4 y = f4[k];
            vf[4*k+0]=y.x; vf[4*k+1]=y.y; vf[4*k+2]=y.z; vf[4*k+3]=y.w;
        }
    }
    const float aL = (t > 0)      ? arow[base - 1]  : 0.0f;  // => a_0 = 0
    const float aR = (t < TB - 1) ? arow[base + CH] : 0.0f;  // => c_{N-1} = 0

    // ---- Phase A: 2x2 cp chunk map [[p,q],[u,v]] on homogeneous (x,z) ----
    float p=1.f, q=0.f, u=0.f, v=1.f;
    #pragma unroll
    for (int k = 0; k < CH; ++k) {
        const float am1 = (k == 0)      ? aL : va[k-1];
        const float ap1 = (k == CH - 1) ? aR : va[k+1];
        const float ai = am1 * am1;
        const float bi = 1.0f + va[k]*va[k]*va[k];
        const float ci = ap1 * (ap1 + 2.0f);
        const float np = ci*u,        nq = ci*v;
        const float nu = bi*u - ai*p, nv = bi*v - ai*q;
        p=np; q=nq; u=nu; v=nv;
    }
    { const float inv = frcp(v); p*=inv; q*=inv; u*=inv; v=1.0f; }

    // ---- forward wave-inclusive shuffle scan (2x2 matmul compose) ----
    #pragma unroll
    for (int off = 1; off < 64; off <<= 1) {
        const float p1=__shfl_up(p,off), q1=__shfl_up(q,off),
                    u1=__shfl_up(u,off), v1=__shfl_up(v,off);
        if (lane >= off) {
            const float np = p*p1 + q*u1, nq = p*q1 + q*v1;
            const float nu = u*p1 + v*u1, nv = u*q1 + v*v1;
            p=np; q=nq; u=nu; v=nv;
        }
    }
    if (lane == 63) { wtot[wid][0]=p; wtot[wid][1]=q; wtot[wid][2]=u; wtot[wid][3]=v; }
    __syncthreads();

    // exclusive-within-wave map
    float ep=__shfl_up(p,1), eq=__shfl_up(q,1), eu=__shfl_up(u,1), ev=__shfl_up(v,1);
    if (lane == 0) { ep=1.f; eq=0.f; eu=0.f; ev=1.f; }

    // prefix over previous waves, COLUMN form: state = T_{w-1}..T_0 * (0,1)^T
    float Pq = 0.f, Pv = 1.f;
    for (int w = 0; w < wid; ++w) {
        const float4 T = *reinterpret_cast<const float4*>(wtot[w]);
        const float nq = T.x*Pq + T.y*Pv;
        const float nv = T.z*Pq + T.w*Pv;
        Pq = nq; Pv = nv;
    }
    float cp;
    {
        const float nx = ep*Pq + eq*Pv;
        const float nz = eu*Pq + ev*Pv;
        cp = nx * frcp(nz);
    }

    // ---- Phase C: homogeneous forward sweep; rcp off the serial chain ----
    // x_k = c_k z_{k-1}; z_k = b_k z_{k-1} - a_k x_{k-1};
    // y_k = f_k z_{k-1} - a_k y_{k-1} (with y linear in dp_in: y = yb + dp_in*al)
    // cp_k = x_k/z_k ; dp_k = (yb_k + dp_in*al_k)/z_k
    float cpv[CH], asv[CH], bsv[CH];
    {
        float xp = cp, zp = 1.0f, yb = 0.0f, al = 1.0f;
        #pragma unroll
        for (int k = 0; k < CH; ++k) {
            const float am1 = (k == 0)      ? aL : va[k-1];
            const float ap1 = (k == CH - 1) ? aR : va[k+1];
            const float ai = am1 * am1;
            const float bi = 1.0f + va[k]*va[k]*va[k];
            const float ci = ap1 * (ap1 + 2.0f);
            const float x = ci * zp;
            const float z = bi*zp - ai*xp;
            const float y = vf[k]*zp - ai*yb;
            al = -ai * al;
            const float rdz = frcp(z);
            cpv[k] = x  * rdz;
            asv[k] = al * rdz;
            bsv[k] = y  * rdz;
            xp = x; zp = z; yb = y;
        }
    }

    // ---- dp affine wave scan: chunk map dp_out = Ad*dp_in + Bd ----
    float Ad = asv[CH-1], Bd = bsv[CH-1];
    #pragma unroll
    for (int off = 1; off < 64; off <<= 1) {
        const float A1 = __shfl_up(Ad, off);
        const float B1 = __shfl_up(Bd, off);
        if (lane >= off) { Bd = Ad*B1 + Bd; Ad = Ad*A1; }
    }
    if (lane == 63) { dtot[wid][0]=Ad; dtot[wid][1]=Bd; }
    __syncthreads();

    float eAd = __shfl_up(Ad,1), eBd = __shfl_up(Bd,1);
    if (lane == 0) { eAd = 1.0f; eBd = 0.0f; }
    float PB = 0.f;  // prefix applied to dp_0 = 0: only B needed
    for (int w = 0; w < wid; ++w) {
        const float2 T = *reinterpret_cast<const float2*>(dtot[w]);
        PB = T.x*PB + T.y;
    }
    const float dp_in = eAd*PB + eBd;

    // ---- materialize dpv; Phase D: backward affine chunk map ----
    float dpv[CH];
    #pragma unroll
    for (int k = 0; k < CH; ++k) dpv[k] = bsv[k] + dp_in*asv[k];

    float A = 1.0f, Bb = 0.0f;
    #pragma unroll
    for (int k = CH - 1; k >= 0; --k) {
        Bb = dpv[k] - cpv[k]*Bb;
        A  = -cpv[k]*A;
    }
    // wave-inclusive suffix scan: comp(mine, later): B = A*B1 + B, A = A*A1
    #pragma unroll
    for (int off = 1; off < 64; off <<= 1) {
        const float A1 = __shfl_down(A, off);
        const float B1 = __shfl_down(Bb, off);
        if (lane < 64 - off) { Bb = A*B1 + Bb; A = A*A1; }
    }
    if (lane == 0) { btot[wid][0] = A; btot[wid][1] = Bb; }
    __syncthreads();

    // exclusive-within-wave suffix
    float eA = __shfl_down(A, 1), eB = __shfl_down(Bb, 1);
    if (lane == 63) { eA = 1.0f; eB = 0.0f; }
    // suffix over later waves applied to u_N = 0: only B needed
    float SB = 0.f;
    for (int w = NWAVE - 1; w > wid; --w) {
        const float2 T = *reinterpret_cast<const float2*>(btot[w]);
        SB = T.x*SB + T.y;
    }
    const float u_in = eA*SB + eB;

    // ---- final back-substitution + float4 stores ----
    float uv[CH];
    float un = u_in;
    #pragma unroll
    for (int k = CH - 1; k >= 0; --k) {
        un = dpv[k] - cpv[k]*un;
        uv[k] = un;
    }
    float4* o4 = reinterpret_cast<float4*>(out + (size_t)row * NN + base);
    #pragma unroll
    for (int k = 0; k < CH / 4; ++k) {
        o4[k] = make_float4(uv[4*k+0], uv[4*k+1], uv[4*k+2], uv[4*k+3]);
    }
}

extern "C" void kernel_launch(void* const* d_in, const int* in_sizes, int n_in,
                              void* d_out, int out_size, void* d_ws, size_t ws_size,
                              hipStream_t stream) {
    const float* alpha = (const float*)d_in[0];
    const float* fvec  = (const float*)d_in[1];
    float* out = (float*)d_out;
    const int nrows = out_size / NN;   // 2048
    thomas_scan_kernel<<<nrows, TB, 0, stream>>>(alpha, fvec, out);
}